// Round 8
// baseline (502.090 us; speedup 1.0000x reference)
//
#include <hip/hip_runtime.h>

constexpr int kB  = 32;
constexpr int kNQ = 256;   // rows n
constexpr int kNT = 512;   // cols m
constexpr float kInf = 1e30f;
constexpr int kSlots = 56;    // LDS row-cache entries
constexpr int kStride = 544;  // 8 groups x (64 data + 4 pad) floats

// Wave64 min-reduction via DPP (rocPRIM pattern). All inputs are non-negative
// float bit-patterns (incl +inf sentinel), so u32 order == f32 order.
__device__ __forceinline__ unsigned wave_min_u32(unsigned x) {
    unsigned t;
    t = (unsigned)__builtin_amdgcn_update_dpp((int)0xFFFFFFFF, (int)x, 0x111, 0xF, 0xF, false); x = t < x ? t : x; // row_shr:1
    t = (unsigned)__builtin_amdgcn_update_dpp((int)0xFFFFFFFF, (int)x, 0x112, 0xF, 0xF, false); x = t < x ? t : x; // row_shr:2
    t = (unsigned)__builtin_amdgcn_update_dpp((int)0xFFFFFFFF, (int)x, 0x114, 0xF, 0xF, false); x = t < x ? t : x; // row_shr:4
    t = (unsigned)__builtin_amdgcn_update_dpp((int)0xFFFFFFFF, (int)x, 0x118, 0xF, 0xF, false); x = t < x ? t : x; // row_shr:8
    t = (unsigned)__builtin_amdgcn_update_dpp((int)0xFFFFFFFF, (int)x, 0x142, 0xF, 0xF, false); x = t < x ? t : x; // row_bcast:15
    t = (unsigned)__builtin_amdgcn_update_dpp((int)0xFFFFFFFF, (int)x, 0x143, 0xF, 0xF, false); x = t < x ? t : x; // row_bcast:31
    return (unsigned)__builtin_amdgcn_readlane((int)x, 63);
}

// ---------------------------------------------------------------------------
// Single fused kernel, 512 threads/block, one block per batch.
//   Phase 0 : stage pose into LDS (overlaid on rowCache — used before any
//             row caching; tags start empty so no interaction).
//   Phase 0b: compute full 256x512 cost tile, thread = target t (layout and
//             expression copied VERBATIM from the proven cost_kernel =>
//             bit-identical values). Per q, lanes write one contiguous 2KB
//             row (coalesced). Queries are wave-uniform loads (scalar).
//   fence+barrier: __syncthreads() semantics drain vmcnt(0) before s_barrier;
//             C addresses were never read before being written => no stale
//             L1 lines. Block reads back its own stores from L2 (512KB/block,
//             4 blocks/XCD => 2MB < 4MB L2, all hits).
//   Phase A/C: EXACT R6 code (proven 356us floor; ARR experiment reverted —
//             R7 measured +71us: auction-without-epsilon price war, and
//             tighter duals did NOT shorten SAP searches).
// ---------------------------------------------------------------------------
__global__ __launch_bounds__(512)
void hungarian_kernel(const float* __restrict__ trans,
                      const float* __restrict__ qpos,
                      const float* __restrict__ rot,
                      const float* __restrict__ pose,
                      float* __restrict__ cost,
                      float* __restrict__ outInds,
                      float* __restrict__ outMask)
{
    __shared__ float rowCache[kSlots * kStride];  // 121856 B (pose overlay: 47104 B)
    __shared__ float u[kNQ];
    __shared__ int   col4row[kNQ];
    __shared__ int   row4col[kNT];
    __shared__ int   colBest[kNT];
    __shared__ int   pathL[kNT];
    __shared__ int   rowArg[kNQ];

    const int b   = blockIdx.x;
    const int tid = threadIdx.x;
    float* __restrict__ Cw = cost + (size_t)b * kNQ * kNT;
    const float* __restrict__ C = Cw;

    // ---- Phase 0: stage pose[b] into LDS (rowCache overlay) ----
    float* sPose = rowCache;
    {
        const float* pb = pose + (size_t)b * kNT * 23;
        for (int idx = tid; idx < kNT * 23; idx += 512) sPose[idx] = pb[idx];
    }
    __syncthreads();

    // ---- Phase 0b: cost tile, thread == target t (verbatim cost math) ----
    {
        float T[23];
        #pragma unroll
        for (int d = 0; d < 23; ++d) T[d] = sPose[tid * 23 + d];

        float s = 0.f;
        #pragma unroll
        for (int d = 0; d < 23; ++d) s += fabsf(T[d]);
        const bool valid = (s > 0.f);

        const float* tr = trans + (size_t)b * kNQ * 3;
        const float* qp = qpos  + (size_t)b * kNQ * 16;
        const float* rt = rot   + (size_t)b * kNQ * 4;

        for (int q = 0; q < kNQ; ++q) {
            const float Q0 = tr[q * 3 + 0], Q1 = tr[q * 3 + 1], Q2 = tr[q * 3 + 2];
            float a = fabsf(Q0 - T[0]);
            a += fabsf(Q1 - T[1]);
            a += fabsf(Q2 - T[2]);
            float bsum = 0.f;
            #pragma unroll
            for (int d = 0; d < 16; ++d) bsum += fabsf(qp[q * 16 + d] - T[3 + d]);
            const float r0 = rt[q * 4 + 0], r1 = rt[q * 4 + 1];
            const float r2 = rt[q * 4 + 2], r3 = rt[q * 4 + 3];
            float dot = r0 * T[19] + r1 * T[20] + r2 * T[21] + r3 * T[22];
            float c = (a + bsum) + (1.0f - fabsf(dot));
            Cw[(size_t)q * kNT + tid] = valid ? c : kInf;
        }
    }
    __threadfence();     // publish stores to L2 (device scope; also no stale L1: C never read before)
    __syncthreads();     // drains vmcnt(0) before s_barrier; rowCache reuse starts fresh

    // ---- Phase A: row minima + greedy matching (thread t == row t) ----
    if (tid < kNQ) {
        const float4* Crow = (const float4*)(C + (size_t)tid * kNT);
        float bm = kInf; int barg = 0;
        #pragma unroll 4
        for (int j4 = 0; j4 < kNT / 4; ++j4) {
            float4 cc = Crow[j4];
            const int jb = j4 * 4;
            if (cc.x < bm) { bm = cc.x; barg = jb + 0; }
            if (cc.y < bm) { bm = cc.y; barg = jb + 1; }
            if (cc.z < bm) { bm = cc.z; barg = jb + 2; }
            if (cc.w < bm) { bm = cc.w; barg = jb + 3; }
        }
        u[tid]      = bm;   // feasible: C - u - 0 >= 0 exactly; matched slack == 0 exactly
        rowArg[tid] = barg;
        col4row[tid] = -1;
    }
    row4col[tid] = -1;
    colBest[tid] = 0x7fffffff;
    __syncthreads();
    if (tid < kNQ) atomicMin(&colBest[rowArg[tid]], tid);
    __syncthreads();
    if (tid < kNQ) {
        const int j = rowArg[tid];
        if (colBest[j] == tid) { col4row[tid] = j; row4col[j] = tid; }
    }
    __syncthreads();

    // ---- Phase C: augmenting searches, wave 0 only (EXACT R6 code) ----
    if (tid < 64) {
        const int lane = tid;
        const int laneOff = (lane >> 3) * 68 + (lane & 7) * 8;
        typedef float v2f __attribute__((ext_vector_type(2)));

        float vR[8];
        #pragma unroll
        for (int c = 0; c < 8; ++c) vR[c] = 0.f;

        int tagReg = -1;   // lane-indexed cache tag (slot == lane)
        int rr     = 0;    // wave-uniform round-robin fill pointer

        for (int cur = 0; cur < kNQ; ++cur) {
            if (col4row[cur] >= 0) continue;   // uniform branch

            float spcR[8]; int pathR[8]; float mskA[8]; float frzV[8]; int frzP[8];
            #pragma unroll
            for (int c = 0; c < 8; ++c) {
                spcR[c] = kInf; pathR[c] = -1; mskA[c] = 0.f;
                frzV[c] = 0.f;  frzP[c] = -1;
            }
            unsigned scMask = 0;

            int   i      = cur;
            float minVal = 0.f;
            int   sink   = -1;

            for (int guard = 0; guard < kNT + 2 && sink < 0; ++guard) {
                const float ui = u[i];            // LDS read, overlaps row fetch
                float4 p0, p1;
                const unsigned long long hm = __ballot(tagReg == i);
                if (hm != 0ull) {                 // cache hit (wave-uniform)
                    const int slot = (int)__ffsll(hm) - 1;
                    const float4* lp = (const float4*)&rowCache[slot * kStride + laneOff];
                    p0 = lp[0]; p1 = lp[1];
                } else {                          // miss: global (L2) load
                    const float4* rp = (const float4*)(C + (size_t)i * kNT + lane * 8);
                    p0 = rp[0]; p1 = rp[1];
                    if (guard != 0) {             // don't cache one-shot cur rows
                        float4* wp = (float4*)&rowCache[rr * kStride + laneOff];
                        wp[0] = p0; wp[1] = p1;   // fire-and-forget
                        if (lane == rr) tagReg = i;
                        rr = rr + 1; if (rr == kSlots) rr = 0;
                    }
                }

                // ---- UNMASKED packed relax (value-exact op order) ----
                const v2f cc2[4] = { {p0.x, p0.y}, {p0.z, p0.w},
                                     {p1.x, p1.y}, {p1.z, p1.w} };
                const v2f mv2 = { minVal, minVal };
                const v2f ui2 = { ui, ui };
                float r8[8];
                #pragma unroll
                for (int p = 0; p < 4; ++p) {
                    const v2f vv = { vR[2*p], vR[2*p + 1] };
                    const v2f rp2 = ((mv2 + cc2[p]) - ui2) - vv;
                    r8[2*p] = rp2.x; r8[2*p + 1] = rp2.y;
                }
                #pragma unroll
                for (int c = 0; c < 8; ++c) {
                    const bool lt = r8[c] < spcR[c];
                    spcR[c]  = lt ? r8[c] : spcR[c];
                    pathR[c] = lt ? i : pathR[c];
                }

                // ---- masked local argmin: msk = spc + {0|+inf}, u32 tree ----
                float mskv[8];
                #pragma unroll
                for (int p = 0; p < 4; ++p) {
                    const v2f s2 = { spcR[2*p], spcR[2*p + 1] };
                    const v2f a2 = { mskA[2*p], mskA[2*p + 1] };
                    const v2f m2 = s2 + a2;
                    mskv[2*p] = m2.x; mskv[2*p + 1] = m2.y;
                }
                unsigned sp[8];
                #pragma unroll
                for (int c = 0; c < 8; ++c) sp[c] = __float_as_uint(mskv[c]);
                unsigned mA = sp[1] < sp[0] ? sp[1] : sp[0]; int aA = sp[1] < sp[0] ? 1 : 0;
                unsigned mB = sp[3] < sp[2] ? sp[3] : sp[2]; int aB = sp[3] < sp[2] ? 3 : 2;
                unsigned mC = sp[5] < sp[4] ? sp[5] : sp[4]; int aC = sp[5] < sp[4] ? 5 : 4;
                unsigned mD = sp[7] < sp[6] ? sp[7] : sp[6]; int aD = sp[7] < sp[6] ? 7 : 6;
                unsigned mAB = mB < mA ? mB : mA; int aAB = mB < mA ? aB : aA;
                unsigned mCD = mD < mC ? mD : mC; int aCD = mD < mC ? aD : aC;
                unsigned lvu = mCD < mAB ? mCD : mAB; int lc = mCD < mAB ? aCD : aAB;
                const int lix  = lane * 8 + lc;
                const int spec = row4col[lix];          // speculative owner prefetch

                const unsigned gmu = wave_min_u32(lvu); // hides the LDS read above
                const unsigned long long bal = __ballot(lvu == gmu);
                const int wl    = (int)__ffsll(bal) - 1;
                const int jstar = __builtin_amdgcn_readlane(lix, wl);
                const int own   = __builtin_amdgcn_readlane(spec, wl);
                minVal = __uint_as_float(gmu);

                if (own < 0) sink = jstar;
                else         i    = own;

                if (wl == lane) {                 // freeze sweep-time state
                    const int lcw = jstar & 7;
                    scMask |= 1u << lcw;
                    #pragma unroll
                    for (int c = 0; c < 8; ++c) {
                        if (c == lcw) {
                            mskA[c] = __builtin_inff();
                            frzV[c] = minVal;     // == spcR[c] at sweep time
                            frzP[c] = pathR[c];
                        }
                    }
                }
            }

            // ---- dual updates (sweep-time values, per swept column) ----
            if (lane == 0) u[cur] += minVal;
            #pragma unroll
            for (int c = 0; c < 8; ++c) {
                if ((scMask >> c) & 1u) {
                    const int j = lane * 8 + c;
                    const int r = row4col[j];
                    const float d = minVal - frzV[c];
                    if (r >= 0) u[r] += d;   // owners distinct (matching invariant)
                    vR[c] -= d;
                    pathL[j] = frzP[c];
                }
            }
            __threadfence_block();

            // ---- augment along alternating path (lane 0) ----
            if (lane == 0 && sink >= 0) {
                int j = sink;
                while (true) {
                    const int pi = pathL[j];
                    row4col[j] = pi;
                    const int nj = col4row[pi];
                    col4row[pi] = j;
                    if (pi == cur) break;
                    j = nj;
                }
            }
            __threadfence_block();
        }
    }
    __syncthreads();

    if (tid < kNQ) {
        outInds[(size_t)b * kNQ + tid] = (float)col4row[tid];
        outMask[(size_t)b * kNQ + tid] = 1.0f;
    }
}

extern "C" void kernel_launch(void* const* d_in, const int* in_sizes, int n_in,
                              void* d_out, int out_size, void* d_ws, size_t ws_size,
                              hipStream_t stream) {
    const float* trans = (const float*)d_in[0];
    const float* qpos  = (const float*)d_in[1];
    const float* rot   = (const float*)d_in[2];
    const float* pose  = (const float*)d_in[3];

    float* out  = (float*)d_out;
    float* cost = out;
    float* inds = out + (size_t)kB * kNQ * kNT;
    float* mask = inds + (size_t)kB * kNQ;

    hungarian_kernel<<<kB, 512, 0, stream>>>(trans, qpos, rot, pose, cost, inds, mask);
}

// Round 10
// 489.833 us; speedup vs baseline: 1.0250x; 1.0250x over previous
//
#include <hip/hip_runtime.h>

constexpr int kB  = 32;
constexpr int kNQ = 256;   // rows n
constexpr int kNT = 512;   // cols m
constexpr float kInf = 1e30f;
constexpr int kSlots = 56;    // LDS row-cache entries
constexpr int kStride = 544;  // 8 groups x (64 data + 4 pad) floats
constexpr int kChunks = 7;    // producer blocks per batch
constexpr int kQChunk = 37;   // ceil(256/7); last chunk covers 34

// Wave64 min-reduction via DPP (rocPRIM pattern). All inputs are non-negative
// float bit-patterns (incl +inf sentinel), so u32 order == f32 order.
__device__ __forceinline__ unsigned wave_min_u32(unsigned x) {
    unsigned t;
    t = (unsigned)__builtin_amdgcn_update_dpp((int)0xFFFFFFFF, (int)x, 0x111, 0xF, 0xF, false); x = t < x ? t : x; // row_shr:1
    t = (unsigned)__builtin_amdgcn_update_dpp((int)0xFFFFFFFF, (int)x, 0x112, 0xF, 0xF, false); x = t < x ? t : x; // row_shr:2
    t = (unsigned)__builtin_amdgcn_update_dpp((int)0xFFFFFFFF, (int)x, 0x114, 0xF, 0xF, false); x = t < x ? t : x; // row_shr:4
    t = (unsigned)__builtin_amdgcn_update_dpp((int)0xFFFFFFFF, (int)x, 0x118, 0xF, 0xF, false); x = t < x ? t : x; // row_shr:8
    t = (unsigned)__builtin_amdgcn_update_dpp((int)0xFFFFFFFF, (int)x, 0x142, 0xF, 0xF, false); x = t < x ? t : x; // row_bcast:15
    t = (unsigned)__builtin_amdgcn_update_dpp((int)0xFFFFFFFF, (int)x, 0x143, 0xF, 0xF, false); x = t < x ? t : x; // row_bcast:31
    return (unsigned)__builtin_amdgcn_readlane((int)x, 63);
}

// ---------------------------------------------------------------------------
// One 256-block launch, 1 block/CU (128KB LDS), two roles:
//   blocks 32..255: PRODUCERS — batch p/7, q-chunk p%7 (37q). Pose->LDS
//     staging + cost expression VERBATIM from the proven cost kernel
//     (bit-identical C). threadfence (device release, L2 writeback) +
//     barrier + one release-atomicAdd on flags[batch].
//   blocks 0..31: CONSUMERS — spin (acquire, agent) until flags[b]==7,
//     then R8's harness-passed 512-thread Phase A/C verbatim.
// Deadlock-impossible: only 32 blocks spin; >=224 CUs free for producers
// under ANY dispatch order. Spin bounded (bug => wrong answer, not hang).
// Cost generation (~31us standalone, R8: 104us when serialized on 32 CUs)
// now overlaps the consumers' spin: ~15us on the critical path.
// ---------------------------------------------------------------------------
__global__ __launch_bounds__(512)
void fused_kernel(const float* __restrict__ trans,
                  const float* __restrict__ qpos,
                  const float* __restrict__ rot,
                  const float* __restrict__ pose,
                  float* __restrict__ cost,
                  float* __restrict__ outInds,
                  float* __restrict__ outMask,
                  unsigned* __restrict__ flags)
{
    __shared__ float rowCache[kSlots * kStride];  // 121856 B (pose overlay in producers)
    __shared__ float u[kNQ];
    __shared__ int   col4row[kNQ];
    __shared__ int   row4col[kNT];
    __shared__ int   colBest[kNT];
    __shared__ int   pathL[kNT];
    __shared__ int   rowArg[kNQ];

    const int tid = threadIdx.x;

    if (blockIdx.x >= 32) {
        // ---------------- PRODUCER ----------------
        const int p     = blockIdx.x - 32;
        const int b     = p / kChunks;
        const int chunk = p - b * kChunks;
        const int q0    = chunk * kQChunk;
        const int q1    = (q0 + kQChunk < kNQ) ? (q0 + kQChunk) : kNQ;

        float* sPose = rowCache;
        const float* pb = pose + (size_t)b * kNT * 23;
        for (int idx = tid; idx < kNT * 23; idx += 512) sPose[idx] = pb[idx];
        __syncthreads();

        float T[23];
        #pragma unroll
        for (int d = 0; d < 23; ++d) T[d] = sPose[tid * 23 + d];
        float s = 0.f;
        #pragma unroll
        for (int d = 0; d < 23; ++d) s += fabsf(T[d]);
        const bool valid = (s > 0.f);

        const float* tr = trans + (size_t)b * kNQ * 3;
        const float* qp = qpos  + (size_t)b * kNQ * 16;
        const float* rt = rot   + (size_t)b * kNQ * 4;
        float* Cw = cost + (size_t)b * kNQ * kNT;

        for (int q = q0; q < q1; ++q) {
            const float Q0 = tr[q * 3 + 0], Q1 = tr[q * 3 + 1], Q2 = tr[q * 3 + 2];
            float a = fabsf(Q0 - T[0]);
            a += fabsf(Q1 - T[1]);
            a += fabsf(Q2 - T[2]);
            float bsum = 0.f;
            #pragma unroll
            for (int d = 0; d < 16; ++d) bsum += fabsf(qp[q * 16 + d] - T[3 + d]);
            const float r0 = rt[q * 4 + 0], r1 = rt[q * 4 + 1];
            const float r2 = rt[q * 4 + 2], r3 = rt[q * 4 + 3];
            float dot = r0 * T[19] + r1 * T[20] + r2 * T[21] + r3 * T[22];
            float c = (a + bsum) + (1.0f - fabsf(dot));
            Cw[(size_t)q * kNT + tid] = valid ? c : kInf;
        }

        __threadfence();     // device-scope release: drain + L2 writeback (cross-XCD)
        __syncthreads();     // all threads' stores/fences complete before signal
        if (tid == 0)
            __hip_atomic_fetch_add(&flags[b], 1u, __ATOMIC_RELEASE,
                                   __HIP_MEMORY_SCOPE_AGENT);
        return;
    }

    // ---------------- CONSUMER ----------------
    const int b = blockIdx.x;
    if (tid == 0) {
        unsigned v = 0; long g = 0;
        do {
            v = __hip_atomic_load(&flags[b], __ATOMIC_ACQUIRE,
                                  __HIP_MEMORY_SCOPE_AGENT);
        } while (v < (unsigned)kChunks && ++g < (1L << 20));  // bounded: bug => wrong, not hang
    }
    __syncthreads();
    __threadfence();         // acquire-side invalidate (belt & braces)

    const float* __restrict__ C = cost + (size_t)b * kNQ * kNT;

    // ---- Phase A: row minima + greedy matching (thread t == row t) ----
    if (tid < kNQ) {
        const float4* Crow = (const float4*)(C + (size_t)tid * kNT);
        float bm = kInf; int barg = 0;
        #pragma unroll 4
        for (int j4 = 0; j4 < kNT / 4; ++j4) {
            float4 cc = Crow[j4];
            const int jb = j4 * 4;
            if (cc.x < bm) { bm = cc.x; barg = jb + 0; }
            if (cc.y < bm) { bm = cc.y; barg = jb + 1; }
            if (cc.z < bm) { bm = cc.z; barg = jb + 2; }
            if (cc.w < bm) { bm = cc.w; barg = jb + 3; }
        }
        u[tid]      = bm;   // feasible: C - u - 0 >= 0 exactly; matched slack == 0 exactly
        rowArg[tid] = barg;
        col4row[tid] = -1;
    }
    row4col[tid] = -1;
    colBest[tid] = 0x7fffffff;
    __syncthreads();
    if (tid < kNQ) atomicMin(&colBest[rowArg[tid]], tid);
    __syncthreads();
    if (tid < kNQ) {
        const int j = rowArg[tid];
        if (colBest[j] == tid) { col4row[tid] = j; row4col[j] = tid; }
    }
    __syncthreads();

    // ---- Phase C: augmenting searches, wave 0 only (EXACT proven code) ----
    if (tid < 64) {
        const int lane = tid;
        const int laneOff = (lane >> 3) * 68 + (lane & 7) * 8;
        typedef float v2f __attribute__((ext_vector_type(2)));

        float vR[8];
        #pragma unroll
        for (int c = 0; c < 8; ++c) vR[c] = 0.f;

        int tagReg = -1;   // lane-indexed cache tag (slot == lane)
        int rr     = 0;    // wave-uniform round-robin fill pointer

        for (int cur = 0; cur < kNQ; ++cur) {
            if (col4row[cur] >= 0) continue;   // uniform branch

            float spcR[8]; int pathR[8]; float mskA[8]; float frzV[8]; int frzP[8];
            #pragma unroll
            for (int c = 0; c < 8; ++c) {
                spcR[c] = kInf; pathR[c] = -1; mskA[c] = 0.f;
                frzV[c] = 0.f;  frzP[c] = -1;
            }
            unsigned scMask = 0;

            int   i      = cur;
            float minVal = 0.f;
            int   sink   = -1;

            for (int guard = 0; guard < kNT + 2 && sink < 0; ++guard) {
                const float ui = u[i];            // LDS read, overlaps row fetch
                float4 p0, p1;
                const unsigned long long hm = __ballot(tagReg == i);
                if (hm != 0ull) {                 // cache hit (wave-uniform)
                    const int slot = (int)__ffsll(hm) - 1;
                    const float4* lp = (const float4*)&rowCache[slot * kStride + laneOff];
                    p0 = lp[0]; p1 = lp[1];
                } else {                          // miss: global (L2) load
                    const float4* rp = (const float4*)(C + (size_t)i * kNT + lane * 8);
                    p0 = rp[0]; p1 = rp[1];
                    if (guard != 0) {             // don't cache one-shot cur rows
                        float4* wp = (float4*)&rowCache[rr * kStride + laneOff];
                        wp[0] = p0; wp[1] = p1;   // fire-and-forget
                        if (lane == rr) tagReg = i;
                        rr = rr + 1; if (rr == kSlots) rr = 0;
                    }
                }

                // ---- UNMASKED packed relax (value-exact op order) ----
                const v2f cc2[4] = { {p0.x, p0.y}, {p0.z, p0.w},
                                     {p1.x, p1.y}, {p1.z, p1.w} };
                const v2f mv2 = { minVal, minVal };
                const v2f ui2 = { ui, ui };
                float r8[8];
                #pragma unroll
                for (int p = 0; p < 4; ++p) {
                    const v2f vv = { vR[2*p], vR[2*p + 1] };
                    const v2f rp2 = ((mv2 + cc2[p]) - ui2) - vv;
                    r8[2*p] = rp2.x; r8[2*p + 1] = rp2.y;
                }
                #pragma unroll
                for (int c = 0; c < 8; ++c) {
                    const bool lt = r8[c] < spcR[c];
                    spcR[c]  = lt ? r8[c] : spcR[c];
                    pathR[c] = lt ? i : pathR[c];
                }

                // ---- masked local argmin: msk = spc + {0|+inf}, u32 tree ----
                float mskv[8];
                #pragma unroll
                for (int p = 0; p < 4; ++p) {
                    const v2f s2 = { spcR[2*p], spcR[2*p + 1] };
                    const v2f a2 = { mskA[2*p], mskA[2*p + 1] };
                    const v2f m2 = s2 + a2;
                    mskv[2*p] = m2.x; mskv[2*p + 1] = m2.y;
                }
                unsigned sp[8];
                #pragma unroll
                for (int c = 0; c < 8; ++c) sp[c] = __float_as_uint(mskv[c]);
                unsigned mA = sp[1] < sp[0] ? sp[1] : sp[0]; int aA = sp[1] < sp[0] ? 1 : 0;
                unsigned mB = sp[3] < sp[2] ? sp[3] : sp[2]; int aB = sp[3] < sp[2] ? 3 : 2;
                unsigned mC = sp[5] < sp[4] ? sp[5] : sp[4]; int aC = sp[5] < sp[4] ? 5 : 4;
                unsigned mD = sp[7] < sp[6] ? sp[7] : sp[6]; int aD = sp[7] < sp[6] ? 7 : 6;
                unsigned mAB = mB < mA ? mB : mA; int aAB = mB < mA ? aB : aA;
                unsigned mCD = mD < mC ? mD : mC; int aCD = mD < mC ? aD : aC;
                unsigned lvu = mCD < mAB ? mCD : mAB; int lc = mCD < mAB ? aCD : aAB;
                const int lix  = lane * 8 + lc;
                const int spec = row4col[lix];          // speculative owner prefetch

                const unsigned gmu = wave_min_u32(lvu); // hides the LDS read above
                const unsigned long long bal = __ballot(lvu == gmu);
                const int wl    = (int)__ffsll(bal) - 1;
                const int jstar = __builtin_amdgcn_readlane(lix, wl);
                const int own   = __builtin_amdgcn_readlane(spec, wl);
                minVal = __uint_as_float(gmu);

                if (own < 0) sink = jstar;
                else         i    = own;

                if (wl == lane) {                 // freeze sweep-time state
                    const int lcw = jstar & 7;
                    scMask |= 1u << lcw;
                    #pragma unroll
                    for (int c = 0; c < 8; ++c) {
                        if (c == lcw) {
                            mskA[c] = __builtin_inff();
                            frzV[c] = minVal;     // == spcR[c] at sweep time
                            frzP[c] = pathR[c];
                        }
                    }
                }
            }

            // ---- dual updates (sweep-time values, per swept column) ----
            if (lane == 0) u[cur] += minVal;
            #pragma unroll
            for (int c = 0; c < 8; ++c) {
                if ((scMask >> c) & 1u) {
                    const int j = lane * 8 + c;
                    const int r = row4col[j];
                    const float d = minVal - frzV[c];
                    if (r >= 0) u[r] += d;   // owners distinct (matching invariant)
                    vR[c] -= d;
                    pathL[j] = frzP[c];
                }
            }
            __threadfence_block();

            // ---- augment along alternating path (lane 0) ----
            if (lane == 0 && sink >= 0) {
                int j = sink;
                while (true) {
                    const int pi = pathL[j];
                    row4col[j] = pi;
                    const int nj = col4row[pi];
                    col4row[pi] = j;
                    if (pi == cur) break;
                    j = nj;
                }
            }
            __threadfence_block();
        }
    }
    __syncthreads();

    if (tid < kNQ) {
        outInds[(size_t)b * kNQ + tid] = (float)col4row[tid];
        outMask[(size_t)b * kNQ + tid] = 1.0f;
    }
}

extern "C" void kernel_launch(void* const* d_in, const int* in_sizes, int n_in,
                              void* d_out, int out_size, void* d_ws, size_t ws_size,
                              hipStream_t stream) {
    const float* trans = (const float*)d_in[0];
    const float* qpos  = (const float*)d_in[1];
    const float* rot   = (const float*)d_in[2];
    const float* pose  = (const float*)d_in[3];

    float* out  = (float*)d_out;
    float* cost = out;
    float* inds = out + (size_t)kB * kNQ * kNT;
    float* mask = inds + (size_t)kB * kNQ;

    unsigned* flags = (unsigned*)d_ws;
    hipMemsetAsync(d_ws, 0, kB * sizeof(unsigned), stream);   // graph-capture legal
    fused_kernel<<<dim3(32 + kB * kChunks), 512, 0, stream>>>(
        trans, qpos, rot, pose, cost, inds, mask, flags);
}

// Round 13
// 425.055 us; speedup vs baseline: 1.1812x; 1.1524x over previous
//
#include <hip/hip_runtime.h>

constexpr int kB  = 32;
constexpr int kNQ = 256;   // rows n
constexpr int kNT = 512;   // cols m
constexpr float kInf = 1e30f;
constexpr int kQTile = 8;     // queries per cost block (grid 1024; proven)
constexpr int kSlots = 64;    // LDS row-cache entries (56->64: max for ballot
                              // scheme = 1 tag/lane; LDS 148480B <= 160K/CU,
                              // R1 proved 146KB works; occupancy unchanged)
constexpr int kStride = 544;  // 8 groups x (64 data + 4 pad) floats

// ---------------------------------------------------------------------------
// Kernel 1: final_cost [B, NQ, NT]. 512 thr/block, thread == target t.
// Math per output element bit-identical to the proven kernel.
// ---------------------------------------------------------------------------
__global__ __launch_bounds__(512)
void cost_kernel(const float* __restrict__ trans,
                 const float* __restrict__ qpos,
                 const float* __restrict__ rot,
                 const float* __restrict__ pose,
                 float* __restrict__ cost)
{
    __shared__ float sPose[kNT * 23];   // 47104 B -> 3 blocks/CU

    const int b     = blockIdx.x;
    const int qBase = blockIdx.y * kQTile;
    const int tid   = threadIdx.x;      // target index t

    const float* pb = pose + (size_t)b * kNT * 23;
    for (int idx = tid; idx < kNT * 23; idx += 512) sPose[idx] = pb[idx];
    __syncthreads();

    float T[23];
    #pragma unroll
    for (int d = 0; d < 23; ++d) T[d] = sPose[tid * 23 + d];

    float s = 0.f;
    #pragma unroll
    for (int d = 0; d < 23; ++d) s += fabsf(T[d]);
    const bool valid = (s > 0.f);

    const float* tr = trans + ((size_t)b * kNQ + qBase) * 3;
    const float* qp = qpos  + ((size_t)b * kNQ + qBase) * 16;
    const float* rt = rot   + ((size_t)b * kNQ + qBase) * 4;
    float* cb = cost + ((size_t)b * kNQ + qBase) * kNT + tid;

    #pragma unroll
    for (int q = 0; q < kQTile; ++q) {
        const float Q0 = tr[q * 3 + 0], Q1 = tr[q * 3 + 1], Q2 = tr[q * 3 + 2];
        float a = fabsf(Q0 - T[0]);
        a += fabsf(Q1 - T[1]);
        a += fabsf(Q2 - T[2]);
        float bsum = 0.f;
        #pragma unroll
        for (int d = 0; d < 16; ++d) bsum += fabsf(qp[q * 16 + d] - T[3 + d]);
        const float r0 = rt[q * 4 + 0], r1 = rt[q * 4 + 1];
        const float r2 = rt[q * 4 + 2], r3 = rt[q * 4 + 3];
        float dot = r0 * T[19] + r1 * T[20] + r2 * T[21] + r3 * T[22];
        float c = (a + bsum) + (1.0f - fabsf(dot));
        cb[(size_t)q * kNT] = valid ? c : kInf;
    }
}

// Wave64 min-reduction via DPP (rocPRIM pattern). All inputs are non-negative
// float bit-patterns (incl +inf sentinel), so u32 order == f32 order.
__device__ __forceinline__ unsigned wave_min_u32(unsigned x) {
    unsigned t;
    t = (unsigned)__builtin_amdgcn_update_dpp((int)0xFFFFFFFF, (int)x, 0x111, 0xF, 0xF, false); x = t < x ? t : x; // row_shr:1
    t = (unsigned)__builtin_amdgcn_update_dpp((int)0xFFFFFFFF, (int)x, 0x112, 0xF, 0xF, false); x = t < x ? t : x; // row_shr:2
    t = (unsigned)__builtin_amdgcn_update_dpp((int)0xFFFFFFFF, (int)x, 0x114, 0xF, 0xF, false); x = t < x ? t : x; // row_shr:4
    t = (unsigned)__builtin_amdgcn_update_dpp((int)0xFFFFFFFF, (int)x, 0x118, 0xF, 0xF, false); x = t < x ? t : x; // row_shr:8
    t = (unsigned)__builtin_amdgcn_update_dpp((int)0xFFFFFFFF, (int)x, 0x142, 0xF, 0xF, false); x = t < x ? t : x; // row_bcast:15
    t = (unsigned)__builtin_amdgcn_update_dpp((int)0xFFFFFFFF, (int)x, 0x143, 0xF, 0xF, false); x = t < x ? t : x; // row_bcast:31
    return (unsigned)__builtin_amdgcn_readlane((int)x, 63);
}

// ---------------------------------------------------------------------------
// Kernel 2: JV LSAP — EXACT R6 code (proven 356us / total 429.2us), only
// kSlots 56->64 (pure cache-capacity change; cached rows are bit-copies, so
// values are unaffected — only hit rate changes).
// Closed experiment ledger (all reverted):
//   R1/R2 reg-state bundle: +54us.  R7 ARR duals: +71us (passed, no SAP gain).
//   R11/R12 column-reduction init: deterministic wrong indices (absmax 495)
//   under BOTH u32 and f32 argmin — "better initial duals" family closed.
//   R8 serial fusion: +31us net.  R10 overlapped fusion: +43us.
// ---------------------------------------------------------------------------
__global__ __launch_bounds__(256)
void hungarian_kernel(const float* __restrict__ cost,
                      float* __restrict__ outInds,
                      float* __restrict__ outMask)
{
    __shared__ float rowCache[kSlots * kStride];  // 139264 B (total 148480 <= 160K)
    __shared__ float u[kNQ];
    __shared__ int   col4row[kNQ];
    __shared__ int   row4col[kNT];
    __shared__ int   colBest[kNT];
    __shared__ int   pathL[kNT];
    __shared__ int   rowArg[kNQ];

    const int b   = blockIdx.x;
    const int tid = threadIdx.x;
    const float* __restrict__ C = cost + (size_t)b * kNQ * kNT;

    // ---- Phase A: row minima + greedy matching (thread t == row t) ----
    {
        const float4* Crow = (const float4*)(C + (size_t)tid * kNT);
        float bm = kInf; int barg = 0;
        #pragma unroll 4
        for (int j4 = 0; j4 < kNT / 4; ++j4) {
            float4 cc = Crow[j4];
            const int jb = j4 * 4;
            if (cc.x < bm) { bm = cc.x; barg = jb + 0; }
            if (cc.y < bm) { bm = cc.y; barg = jb + 1; }
            if (cc.z < bm) { bm = cc.z; barg = jb + 2; }
            if (cc.w < bm) { bm = cc.w; barg = jb + 3; }
        }
        u[tid]      = bm;   // feasible: C - u - 0 >= 0 exactly; matched slack == 0 exactly
        rowArg[tid] = barg;
        col4row[tid] = -1;
    }
    row4col[tid] = -1;         row4col[tid + 256] = -1;
    colBest[tid] = 0x7fffffff; colBest[tid + 256] = 0x7fffffff;
    __syncthreads();
    atomicMin(&colBest[rowArg[tid]], tid);
    __syncthreads();
    {
        const int j = rowArg[tid];
        if (colBest[j] == tid) { col4row[tid] = j; row4col[j] = tid; }
    }
    __syncthreads();

    // ---- Phase C: augmenting searches, wave 0 only (wave-synchronous) ----
    if (tid < 64) {
        const int lane = tid;
        const int laneOff = (lane >> 3) * 68 + (lane & 7) * 8;
        typedef float v2f __attribute__((ext_vector_type(2)));

        float vR[8];
        #pragma unroll
        for (int c = 0; c < 8; ++c) vR[c] = 0.f;

        int tagReg = -1;   // lane-indexed cache tag (slot == lane)
        int rr     = 0;    // wave-uniform round-robin fill pointer

        for (int cur = 0; cur < kNQ; ++cur) {
            if (col4row[cur] >= 0) continue;   // uniform branch

            float spcR[8]; int pathR[8]; float mskA[8]; float frzV[8]; int frzP[8];
            #pragma unroll
            for (int c = 0; c < 8; ++c) {
                spcR[c] = kInf; pathR[c] = -1; mskA[c] = 0.f;
                frzV[c] = 0.f;  frzP[c] = -1;
            }
            unsigned scMask = 0;

            int   i      = cur;
            float minVal = 0.f;
            int   sink   = -1;

            for (int guard = 0; guard < kNT + 2 && sink < 0; ++guard) {
                const float ui = u[i];            // LDS read, overlaps row fetch
                float4 p0, p1;
                const unsigned long long hm = __ballot(tagReg == i);
                if (hm != 0ull) {                 // cache hit (wave-uniform)
                    const int slot = (int)__ffsll(hm) - 1;
                    const float4* lp = (const float4*)&rowCache[slot * kStride + laneOff];
                    p0 = lp[0]; p1 = lp[1];
                } else {                          // miss: global (L2) load
                    const float4* rp = (const float4*)(C + (size_t)i * kNT + lane * 8);
                    p0 = rp[0]; p1 = rp[1];
                    if (guard != 0) {             // don't cache one-shot cur rows
                        float4* wp = (float4*)&rowCache[rr * kStride + laneOff];
                        wp[0] = p0; wp[1] = p1;   // fire-and-forget
                        if (lane == rr) tagReg = i;
                        rr = rr + 1; if (rr == kSlots) rr = 0;
                    }
                }

                // ---- UNMASKED packed relax (value-exact op order) ----
                const v2f cc2[4] = { {p0.x, p0.y}, {p0.z, p0.w},
                                     {p1.x, p1.y}, {p1.z, p1.w} };
                const v2f mv2 = { minVal, minVal };
                const v2f ui2 = { ui, ui };
                float r8[8];
                #pragma unroll
                for (int p = 0; p < 4; ++p) {
                    const v2f vv = { vR[2*p], vR[2*p + 1] };
                    const v2f rp2 = ((mv2 + cc2[p]) - ui2) - vv;
                    r8[2*p] = rp2.x; r8[2*p + 1] = rp2.y;
                }
                #pragma unroll
                for (int c = 0; c < 8; ++c) {
                    const bool lt = r8[c] < spcR[c];
                    spcR[c]  = lt ? r8[c] : spcR[c];
                    pathR[c] = lt ? i : pathR[c];
                }

                // ---- masked local argmin: msk = spc + {0|+inf}, u32 tree ----
                float mskv[8];
                #pragma unroll
                for (int p = 0; p < 4; ++p) {
                    const v2f s2 = { spcR[2*p], spcR[2*p + 1] };
                    const v2f a2 = { mskA[2*p], mskA[2*p + 1] };
                    const v2f m2 = s2 + a2;
                    mskv[2*p] = m2.x; mskv[2*p + 1] = m2.y;
                }
                unsigned sp[8];
                #pragma unroll
                for (int c = 0; c < 8; ++c) sp[c] = __float_as_uint(mskv[c]);
                unsigned mA = sp[1] < sp[0] ? sp[1] : sp[0]; int aA = sp[1] < sp[0] ? 1 : 0;
                unsigned mB = sp[3] < sp[2] ? sp[3] : sp[2]; int aB = sp[3] < sp[2] ? 3 : 2;
                unsigned mC = sp[5] < sp[4] ? sp[5] : sp[4]; int aC = sp[5] < sp[4] ? 5 : 4;
                unsigned mD = sp[7] < sp[6] ? sp[7] : sp[6]; int aD = sp[7] < sp[6] ? 7 : 6;
                unsigned mAB = mB < mA ? mB : mA; int aAB = mB < mA ? aB : aA;
                unsigned mCD = mD < mC ? mD : mC; int aCD = mD < mC ? aD : aC;
                unsigned lvu = mCD < mAB ? mCD : mAB; int lc = mCD < mAB ? aCD : aAB;
                const int lix  = lane * 8 + lc;
                const int spec = row4col[lix];          // speculative owner prefetch

                const unsigned gmu = wave_min_u32(lvu); // hides the LDS read above
                const unsigned long long bal = __ballot(lvu == gmu);
                const int wl    = (int)__ffsll(bal) - 1;
                const int jstar = __builtin_amdgcn_readlane(lix, wl);
                const int own   = __builtin_amdgcn_readlane(spec, wl);
                minVal = __uint_as_float(gmu);

                if (own < 0) sink = jstar;
                else         i    = own;

                if (wl == lane) {                 // freeze sweep-time state
                    const int lcw = jstar & 7;
                    scMask |= 1u << lcw;
                    #pragma unroll
                    for (int c = 0; c < 8; ++c) {
                        if (c == lcw) {
                            mskA[c] = __builtin_inff();
                            frzV[c] = minVal;     // == spcR[c] at sweep time
                            frzP[c] = pathR[c];
                        }
                    }
                }
            }

            // ---- dual updates (sweep-time values, per swept column) ----
            if (lane == 0) u[cur] += minVal;
            #pragma unroll
            for (int c = 0; c < 8; ++c) {
                if ((scMask >> c) & 1u) {
                    const int j = lane * 8 + c;
                    const int r = row4col[j];
                    const float d = minVal - frzV[c];
                    if (r >= 0) u[r] += d;   // owners distinct (matching invariant)
                    vR[c] -= d;
                    pathL[j] = frzP[c];
                }
            }
            __threadfence_block();

            // ---- augment along alternating path (lane 0) ----
            if (lane == 0 && sink >= 0) {
                int j = sink;
                while (true) {
                    const int pi = pathL[j];
                    row4col[j] = pi;
                    const int nj = col4row[pi];
                    col4row[pi] = j;
                    if (pi == cur) break;
                    j = nj;
                }
            }
            __threadfence_block();
        }
    }
    __syncthreads();

    outInds[(size_t)b * kNQ + tid] = (float)col4row[tid];
    outMask[(size_t)b * kNQ + tid] = 1.0f;
}

extern "C" void kernel_launch(void* const* d_in, const int* in_sizes, int n_in,
                              void* d_out, int out_size, void* d_ws, size_t ws_size,
                              hipStream_t stream) {
    const float* trans = (const float*)d_in[0];
    const float* qpos  = (const float*)d_in[1];
    const float* rot   = (const float*)d_in[2];
    const float* pose  = (const float*)d_in[3];

    float* out  = (float*)d_out;
    float* cost = out;
    float* inds = out + (size_t)kB * kNQ * kNT;
    float* mask = inds + (size_t)kB * kNQ;

    dim3 g1(kB, kNQ / kQTile);
    cost_kernel<<<g1, 512, 0, stream>>>(trans, qpos, rot, pose, cost);
    hungarian_kernel<<<kB, 256, 0, stream>>>(cost, inds, mask);
}

// Round 14
// 424.908 us; speedup vs baseline: 1.1816x; 1.0003x over previous
//
#include <hip/hip_runtime.h>

constexpr int kB  = 32;
constexpr int kNQ = 256;   // rows n
constexpr int kNT = 512;   // cols m
constexpr float kInf = 1e30f;
constexpr int kQTile = 8;     // queries per cost block (grid 1024; proven)
constexpr int kSlots = 64;    // LDS row-cache entries (proven R13: -3.5us vs 56)
constexpr int kStride = 544;  // 8 groups x (64 data + 4 pad) floats

// ---------------------------------------------------------------------------
// Kernel 1: final_cost [B, NQ, NT]. 512 thr/block, thread == target t.
// Math per output element bit-identical to the proven kernel.
// ---------------------------------------------------------------------------
__global__ __launch_bounds__(512)
void cost_kernel(const float* __restrict__ trans,
                 const float* __restrict__ qpos,
                 const float* __restrict__ rot,
                 const float* __restrict__ pose,
                 float* __restrict__ cost)
{
    __shared__ float sPose[kNT * 23];   // 47104 B -> 3 blocks/CU

    const int b     = blockIdx.x;
    const int qBase = blockIdx.y * kQTile;
    const int tid   = threadIdx.x;      // target index t

    const float* pb = pose + (size_t)b * kNT * 23;
    for (int idx = tid; idx < kNT * 23; idx += 512) sPose[idx] = pb[idx];
    __syncthreads();

    float T[23];
    #pragma unroll
    for (int d = 0; d < 23; ++d) T[d] = sPose[tid * 23 + d];

    float s = 0.f;
    #pragma unroll
    for (int d = 0; d < 23; ++d) s += fabsf(T[d]);
    const bool valid = (s > 0.f);

    const float* tr = trans + ((size_t)b * kNQ + qBase) * 3;
    const float* qp = qpos  + ((size_t)b * kNQ + qBase) * 16;
    const float* rt = rot   + ((size_t)b * kNQ + qBase) * 4;
    float* cb = cost + ((size_t)b * kNQ + qBase) * kNT + tid;

    #pragma unroll
    for (int q = 0; q < kQTile; ++q) {
        const float Q0 = tr[q * 3 + 0], Q1 = tr[q * 3 + 1], Q2 = tr[q * 3 + 2];
        float a = fabsf(Q0 - T[0]);
        a += fabsf(Q1 - T[1]);
        a += fabsf(Q2 - T[2]);
        float bsum = 0.f;
        #pragma unroll
        for (int d = 0; d < 16; ++d) bsum += fabsf(qp[q * 16 + d] - T[3 + d]);
        const float r0 = rt[q * 4 + 0], r1 = rt[q * 4 + 1];
        const float r2 = rt[q * 4 + 2], r3 = rt[q * 4 + 3];
        float dot = r0 * T[19] + r1 * T[20] + r2 * T[21] + r3 * T[22];
        float c = (a + bsum) + (1.0f - fabsf(dot));
        cb[(size_t)q * kNT] = valid ? c : kInf;
    }
}

// Wave64 min-reduction via DPP (rocPRIM pattern). All inputs are non-negative
// float bit-patterns (incl +inf sentinel), so u32 order == f32 order.
__device__ __forceinline__ unsigned wave_min_u32(unsigned x) {
    unsigned t;
    t = (unsigned)__builtin_amdgcn_update_dpp((int)0xFFFFFFFF, (int)x, 0x111, 0xF, 0xF, false); x = t < x ? t : x; // row_shr:1
    t = (unsigned)__builtin_amdgcn_update_dpp((int)0xFFFFFFFF, (int)x, 0x112, 0xF, 0xF, false); x = t < x ? t : x; // row_shr:2
    t = (unsigned)__builtin_amdgcn_update_dpp((int)0xFFFFFFFF, (int)x, 0x114, 0xF, 0xF, false); x = t < x ? t : x; // row_shr:4
    t = (unsigned)__builtin_amdgcn_update_dpp((int)0xFFFFFFFF, (int)x, 0x118, 0xF, 0xF, false); x = t < x ? t : x; // row_shr:8
    t = (unsigned)__builtin_amdgcn_update_dpp((int)0xFFFFFFFF, (int)x, 0x142, 0xF, 0xF, false); x = t < x ? t : x; // row_bcast:15
    t = (unsigned)__builtin_amdgcn_update_dpp((int)0xFFFFFFFF, (int)x, 0x143, 0xF, 0xF, false); x = t < x ? t : x; // row_bcast:31
    return (unsigned)__builtin_amdgcn_readlane((int)x, 63);
}

// ---------------------------------------------------------------------------
// Kernel 2: JV LSAP — Phase A/C byte-identical to the proven R13 kernel
// (353us / total 425.05us). NEW: waves 1-3 (previously idle between Phase A
// and the exit barrier) STREAM this block's 512KB cost matrix once — pure
// reads with asm keepalive — pulling C[b] into the LOCAL XCD L2 (4 blocks/
// XCD x 512KB = 2MB < 4MB). The cost kernel's 1024-block grid scattered each
// batch's lines across all 8 XCDs' L2s, so wave 0's row-cache misses paid
// cross-XCD latency (~400-900cy); after ~15us of streaming they pay local-L2
// (~200cy). No shared state touched; no extra barriers; semantics unchanged.
// ---------------------------------------------------------------------------
__global__ __launch_bounds__(256)
void hungarian_kernel(const float* __restrict__ cost,
                      float* __restrict__ outInds,
                      float* __restrict__ outMask)
{
    __shared__ float rowCache[kSlots * kStride];  // 139264 B (total 148480 <= 160K)
    __shared__ float u[kNQ];
    __shared__ int   col4row[kNQ];
    __shared__ int   row4col[kNT];
    __shared__ int   colBest[kNT];
    __shared__ int   pathL[kNT];
    __shared__ int   rowArg[kNQ];

    const int b   = blockIdx.x;
    const int tid = threadIdx.x;
    const float* __restrict__ C = cost + (size_t)b * kNQ * kNT;

    // ---- Phase A: row minima + greedy matching (thread t == row t) ----
    {
        const float4* Crow = (const float4*)(C + (size_t)tid * kNT);
        float bm = kInf; int barg = 0;
        #pragma unroll 4
        for (int j4 = 0; j4 < kNT / 4; ++j4) {
            float4 cc = Crow[j4];
            const int jb = j4 * 4;
            if (cc.x < bm) { bm = cc.x; barg = jb + 0; }
            if (cc.y < bm) { bm = cc.y; barg = jb + 1; }
            if (cc.z < bm) { bm = cc.z; barg = jb + 2; }
            if (cc.w < bm) { bm = cc.w; barg = jb + 3; }
        }
        u[tid]      = bm;   // feasible: C - u - 0 >= 0 exactly; matched slack == 0 exactly
        rowArg[tid] = barg;
        col4row[tid] = -1;
    }
    row4col[tid] = -1;         row4col[tid + 256] = -1;
    colBest[tid] = 0x7fffffff; colBest[tid + 256] = 0x7fffffff;
    __syncthreads();
    atomicMin(&colBest[rowArg[tid]], tid);
    __syncthreads();
    {
        const int j = rowArg[tid];
        if (colBest[j] == tid) { col4row[tid] = j; row4col[j] = tid; }
    }
    __syncthreads();

    // ---- Phase C: augmenting searches, wave 0 only (wave-synchronous) ----
    if (tid < 64) {
        const int lane = tid;
        const int laneOff = (lane >> 3) * 68 + (lane & 7) * 8;
        typedef float v2f __attribute__((ext_vector_type(2)));

        float vR[8];
        #pragma unroll
        for (int c = 0; c < 8; ++c) vR[c] = 0.f;

        int tagReg = -1;   // lane-indexed cache tag (slot == lane)
        int rr     = 0;    // wave-uniform round-robin fill pointer

        for (int cur = 0; cur < kNQ; ++cur) {
            if (col4row[cur] >= 0) continue;   // uniform branch

            float spcR[8]; int pathR[8]; float mskA[8]; float frzV[8]; int frzP[8];
            #pragma unroll
            for (int c = 0; c < 8; ++c) {
                spcR[c] = kInf; pathR[c] = -1; mskA[c] = 0.f;
                frzV[c] = 0.f;  frzP[c] = -1;
            }
            unsigned scMask = 0;

            int   i      = cur;
            float minVal = 0.f;
            int   sink   = -1;

            for (int guard = 0; guard < kNT + 2 && sink < 0; ++guard) {
                const float ui = u[i];            // LDS read, overlaps row fetch
                float4 p0, p1;
                const unsigned long long hm = __ballot(tagReg == i);
                if (hm != 0ull) {                 // cache hit (wave-uniform)
                    const int slot = (int)__ffsll(hm) - 1;
                    const float4* lp = (const float4*)&rowCache[slot * kStride + laneOff];
                    p0 = lp[0]; p1 = lp[1];
                } else {                          // miss: global (L2) load
                    const float4* rp = (const float4*)(C + (size_t)i * kNT + lane * 8);
                    p0 = rp[0]; p1 = rp[1];
                    if (guard != 0) {             // don't cache one-shot cur rows
                        float4* wp = (float4*)&rowCache[rr * kStride + laneOff];
                        wp[0] = p0; wp[1] = p1;   // fire-and-forget
                        if (lane == rr) tagReg = i;
                        rr = rr + 1; if (rr == kSlots) rr = 0;
                    }
                }

                // ---- UNMASKED packed relax (value-exact op order) ----
                const v2f cc2[4] = { {p0.x, p0.y}, {p0.z, p0.w},
                                     {p1.x, p1.y}, {p1.z, p1.w} };
                const v2f mv2 = { minVal, minVal };
                const v2f ui2 = { ui, ui };
                float r8[8];
                #pragma unroll
                for (int p = 0; p < 4; ++p) {
                    const v2f vv = { vR[2*p], vR[2*p + 1] };
                    const v2f rp2 = ((mv2 + cc2[p]) - ui2) - vv;
                    r8[2*p] = rp2.x; r8[2*p + 1] = rp2.y;
                }
                #pragma unroll
                for (int c = 0; c < 8; ++c) {
                    const bool lt = r8[c] < spcR[c];
                    spcR[c]  = lt ? r8[c] : spcR[c];
                    pathR[c] = lt ? i : pathR[c];
                }

                // ---- masked local argmin: msk = spc + {0|+inf}, u32 tree ----
                float mskv[8];
                #pragma unroll
                for (int p = 0; p < 4; ++p) {
                    const v2f s2 = { spcR[2*p], spcR[2*p + 1] };
                    const v2f a2 = { mskA[2*p], mskA[2*p + 1] };
                    const v2f m2 = s2 + a2;
                    mskv[2*p] = m2.x; mskv[2*p + 1] = m2.y;
                }
                unsigned sp[8];
                #pragma unroll
                for (int c = 0; c < 8; ++c) sp[c] = __float_as_uint(mskv[c]);
                unsigned mA = sp[1] < sp[0] ? sp[1] : sp[0]; int aA = sp[1] < sp[0] ? 1 : 0;
                unsigned mB = sp[3] < sp[2] ? sp[3] : sp[2]; int aB = sp[3] < sp[2] ? 3 : 2;
                unsigned mC = sp[5] < sp[4] ? sp[5] : sp[4]; int aC = sp[5] < sp[4] ? 5 : 4;
                unsigned mD = sp[7] < sp[6] ? sp[7] : sp[6]; int aD = sp[7] < sp[6] ? 7 : 6;
                unsigned mAB = mB < mA ? mB : mA; int aAB = mB < mA ? aB : aA;
                unsigned mCD = mD < mC ? mD : mC; int aCD = mD < mC ? aD : aC;
                unsigned lvu = mCD < mAB ? mCD : mAB; int lc = mCD < mAB ? aCD : aAB;
                const int lix  = lane * 8 + lc;
                const int spec = row4col[lix];          // speculative owner prefetch

                const unsigned gmu = wave_min_u32(lvu); // hides the LDS read above
                const unsigned long long bal = __ballot(lvu == gmu);
                const int wl    = (int)__ffsll(bal) - 1;
                const int jstar = __builtin_amdgcn_readlane(lix, wl);
                const int own   = __builtin_amdgcn_readlane(spec, wl);
                minVal = __uint_as_float(gmu);

                if (own < 0) sink = jstar;
                else         i    = own;

                if (wl == lane) {                 // freeze sweep-time state
                    const int lcw = jstar & 7;
                    scMask |= 1u << lcw;
                    #pragma unroll
                    for (int c = 0; c < 8; ++c) {
                        if (c == lcw) {
                            mskA[c] = __builtin_inff();
                            frzV[c] = minVal;     // == spcR[c] at sweep time
                            frzP[c] = pathR[c];
                        }
                    }
                }
            }

            // ---- dual updates (sweep-time values, per swept column) ----
            if (lane == 0) u[cur] += minVal;
            #pragma unroll
            for (int c = 0; c < 8; ++c) {
                if ((scMask >> c) & 1u) {
                    const int j = lane * 8 + c;
                    const int r = row4col[j];
                    const float d = minVal - frzV[c];
                    if (r >= 0) u[r] += d;   // owners distinct (matching invariant)
                    vR[c] -= d;
                    pathL[j] = frzP[c];
                }
            }
            __threadfence_block();

            // ---- augment along alternating path (lane 0) ----
            if (lane == 0 && sink >= 0) {
                int j = sink;
                while (true) {
                    const int pi = pathL[j];
                    row4col[j] = pi;
                    const int nj = col4row[pi];
                    col4row[pi] = j;
                    if (pi == cur) break;
                    j = nj;
                }
            }
            __threadfence_block();
        }
    } else {
        // ---- waves 1-3: stream C[b] once to pull it into the local XCD L2.
        //      Pure reads; asm keepalive prevents DCE (rule #17). No shared
        //      state, no barriers — rejoins at the final __syncthreads().
        const int w    = (tid >> 6) - 1;   // 0..2
        const int lane = tid & 63;
        float a0 = 0.f, a1 = 0.f;
        for (int r = w; r < kNQ; r += 3) {
            const float4* rp = (const float4*)(C + (size_t)r * kNT);
            const float4 x = rp[lane];        // 64 lanes x 16B = first 1KB
            const float4 y = rp[lane + 64];   // second 1KB of the 2KB row
            a0 += x.x; a1 += y.x;
        }
        asm volatile("" :: "v"(a0), "v"(a1));
    }
    __syncthreads();

    outInds[(size_t)b * kNQ + tid] = (float)col4row[tid];
    outMask[(size_t)b * kNQ + tid] = 1.0f;
}

extern "C" void kernel_launch(void* const* d_in, const int* in_sizes, int n_in,
                              void* d_out, int out_size, void* d_ws, size_t ws_size,
                              hipStream_t stream) {
    const float* trans = (const float*)d_in[0];
    const float* qpos  = (const float*)d_in[1];
    const float* rot   = (const float*)d_in[2];
    const float* pose  = (const float*)d_in[3];

    float* out  = (float*)d_out;
    float* cost = out;
    float* inds = out + (size_t)kB * kNQ * kNT;
    float* mask = inds + (size_t)kB * kNQ;

    dim3 g1(kB, kNQ / kQTile);
    cost_kernel<<<g1, 512, 0, stream>>>(trans, qpos, rot, pose, cost);
    hungarian_kernel<<<kB, 256, 0, stream>>>(cost, inds, mask);
}